// Round 9
// baseline (153.406 us; speedup 1.0000x reference)
//
#include <hip/hip_runtime.h>
#include <hip/hip_bf16.h>
#include <math.h>

#define Bb 8
#define Tt 512
#define Cc 512
#define Hh 8
#define HKV 4
#define Dd 64

typedef __attribute__((ext_vector_type(8))) short short8;
typedef __attribute__((ext_vector_type(4))) float float4v;
typedef __attribute__((ext_vector_type(2))) __fp16 h2;   // matches cvt_pkrtz return
typedef __attribute__((ext_vector_type(8))) __fp16 half8; // f16 MFMA fragment

__device__ __forceinline__ h2 u2h(unsigned u) {
  union { unsigned u; h2 h; } x; x.u = u; return x.h;
}
__device__ __forceinline__ unsigned h2u(h2 h) {
  union { h2 h; unsigned u; } x; x.h = h; return x.u;
}
__device__ __forceinline__ float fdot2(h2 a, h2 b, float c) {
#if __has_builtin(__builtin_amdgcn_fdot2)
  return __builtin_amdgcn_fdot2(a, b, c, false);
#else
  return fmaf((float)a.x, (float)b.x, fmaf((float)a.y, (float)b.y, c));
#endif
}

__device__ __forceinline__ float wave_reduce_sum(float v) {
#pragma unroll
  for (int off = 32; off > 0; off >>= 1) v += __shfl_xor(v, off, 64);
  return v;
}
__device__ __forceinline__ unsigned pack_bf2(float a, float b) {
  __hip_bfloat162 h = __float22bfloat162_rn(make_float2(a, b));
  return *(unsigned*)&h;
}

// ---------------- fused prep: conv_x | conv_w | build_pw (by block range) ----------------
__global__ __launch_bounds__(256) void prep(
    const float* __restrict__ x, const float* __restrict__ Wq,
    const float* __restrict__ Wk, const float* __restrict__ Wv,
    const float* __restrict__ Wp, const float* __restrict__ P,
    const float* __restrict__ sigma,
    unsigned short* __restrict__ xb, unsigned short* __restrict__ Wtq,
    unsigned short* __restrict__ Wtp, unsigned short* __restrict__ Pwh) {
  const int bid = blockIdx.x;
  const int t = threadIdx.x;
  if (bid < 1024) {
    int i = (bid * 256 + t) * 8;
    float4 f0 = *(const float4*)&x[i];
    float4 f1 = *(const float4*)&x[i + 4];
    unsigned u[4] = {pack_bf2(f0.x, f0.y), pack_bf2(f0.z, f0.w),
                     pack_bf2(f1.x, f1.y), pack_bf2(f1.z, f1.w)};
    *(uint4*)&xb[i] = *(uint4*)u;
  } else if (bid < 1216) {
    __shared__ float Ts[64][65];
    const int bx = bid - 1024;
    const int k0 = (bx & 7) << 6;
    const int n0 = (bx >> 3) << 6;
    const float* src; int ld, nc0; unsigned short* dst; int ndst;
    if (n0 < 512)       { src = Wq; ld = 512; nc0 = n0;        dst = Wtq; ndst = n0; }
    else if (n0 < 768)  { src = Wk; ld = 256; nc0 = n0 - 512;  dst = Wtq; ndst = n0; }
    else if (n0 < 1024) { src = Wv; ld = 256; nc0 = n0 - 768;  dst = Wtq; ndst = n0; }
    else                { src = Wp; ld = 512; nc0 = n0 - 1024; dst = Wtp; ndst = n0 - 1024; }
    const int r = t >> 4, c4 = (t & 15) << 2;
#pragma unroll
    for (int rr = 0; rr < 4; ++rr) {
      int row = (rr << 4) + r;
      float4 f = *(const float4*)&src[(k0 + row) * ld + nc0 + c4];
      Ts[row][c4] = f.x; Ts[row][c4 + 1] = f.y;
      Ts[row][c4 + 2] = f.z; Ts[row][c4 + 3] = f.w;
    }
    __syncthreads();
#pragma unroll
    for (int rr = 0; rr < 4; ++rr) {
      int nr = (rr << 4) + r;
      unsigned u0 = pack_bf2(Ts[c4][nr], Ts[c4 + 1][nr]);
      unsigned u1 = pack_bf2(Ts[c4 + 2][nr], Ts[c4 + 3][nr]);
      *(uint2*)&dst[(ndst + nr) * 512 + k0 + c4] = make_uint2(u0, u1);
    }
  } else {
    int idx = (bid - 1216) * 256 + t;
    int d = idx & 63;
    int rem = idx >> 6;
    int dd = rem % 1023;
    int h = rem / 1023;
    float s = fabsf(sigma[h]) + 1e-6f;
    float delta = (float)(dd - 511);
    float dt = 128.0f * tanhf(delta / s) + 128.0f;
    float lo = floorf(dt);
    int ilo = (int)lo;
    float frac = dt - lo;
    ilo = max(0, min(ilo, 256));
    int ihi = min(ilo + 1, 256);
    const float* Pb = P + h * 257 * 64;
    float val = (1.0f - frac) * Pb[ilo * 64 + d] + frac * Pb[ihi * 64 + d];
    __fp16 hv = (__fp16)val;
    Pwh[idx] = *(unsigned short*)&hv;
  }
}

// ---------------- QKV MFMA GEMM v16: 128x128 tile (guide ladder step 2) ----------------
// 64^2 tile ~ 343 TF class; 128^2 with 4x4 frags/wave ~ 517 TF (m93). Grid 32x8 = 256
// blocks = 1/CU; 32 MFMA per wave per k-iter vs 8 -> 4x better MFMA:overhead ratio.
// Each wave owns a 64x64 quadrant whose column span aligns exactly to one head.
// sm_scale (1/8) folded into the q store (attn uses raw sr).
__global__ __launch_bounds__(256) void qkv_mfma(
    const unsigned short* __restrict__ xb, const unsigned short* __restrict__ Wt,
    unsigned short* __restrict__ qh, unsigned short* __restrict__ kh,
    unsigned short* __restrict__ vT) {
  __shared__ unsigned short As[128][72];
  __shared__ unsigned short Bs[128][72];
  const int m0 = blockIdx.x * 128;
  const int n0 = blockIdx.y * 128;
  const int t = threadIdx.x;
  const int w = t >> 6, lane = t & 63;
  const int wr = (w >> 1) << 6;       // wave row offset: 0/64
  const int wc = (w & 1) << 6;        // wave col offset: 0/64
  const int l15 = lane & 15;
  const int kq = (lane >> 4) << 3;
  float4v acc[4][4] = {};
  for (int k0 = 0; k0 < 512; k0 += 64) {
    uint4 a[4], b[4];
#pragma unroll
    for (int i = 0; i < 4; ++i) {
      int c = (i << 8) + t, r = c >> 3, cc = (c & 7) << 3;
      a[i] = *(const uint4*)&xb[(m0 + r) * 512 + k0 + cc];
      b[i] = *(const uint4*)&Wt[(n0 + r) * 512 + k0 + cc];
    }
    __syncthreads();
#pragma unroll
    for (int i = 0; i < 4; ++i) {
      int c = (i << 8) + t, r = c >> 3, cc = (c & 7) << 3;
      *(uint4*)&As[r][cc] = a[i];
      *(uint4*)&Bs[r][cc] = b[i];
    }
    __syncthreads();
#pragma unroll
    for (int kk = 0; kk < 2; ++kk) {
      short8 aF[4];
#pragma unroll
      for (int mt = 0; mt < 4; ++mt)
        aF[mt] = *(short8*)&As[wr + (mt << 4) + l15][kq + (kk << 5)];
#pragma unroll
      for (int nt = 0; nt < 4; ++nt) {
        short8 bF = *(short8*)&Bs[wc + (nt << 4) + l15][kq + (kk << 5)];
#pragma unroll
        for (int mt = 0; mt < 4; ++mt)
          acc[mt][nt] = __builtin_amdgcn_mfma_f32_16x16x32_bf16(aF[mt], bF, acc[mt][nt], 0, 0, 0);
      }
    }
  }
  const int nc0 = n0 + wc;             // wave's first col; 64-aligned head boundary
  const int rowq = (lane >> 4) << 2;   // quad row base 0/4/8/12
  if (nc0 < 768) {
    // q or k head: fused RMS-norm over the 64-wide head (= this wave's col span)
#pragma unroll
    for (int mt = 0; mt < 4; ++mt) {
#pragma unroll
      for (int r = 0; r < 4; ++r) {
        float ss = 0.0f;
#pragma unroll
        for (int nt = 0; nt < 4; ++nt) ss = fmaf(acc[mt][nt][r], acc[mt][nt][r], ss);
#pragma unroll
        for (int off = 1; off < 16; off <<= 1) ss += __shfl_xor(ss, off, 64);
        float sc2 = 8.0f * rsqrtf(ss + 1e-6f);
        const int row = m0 + wr + (mt << 4) + rowq + r;
        if (nc0 < 512) {
          const int h = nc0 >> 6;
          const float sc3 = sc2 * 0.125f;   // fold sm_scale into q
#pragma unroll
          for (int nt = 0; nt < 4; ++nt) {
            __fp16 hv = (__fp16)(acc[mt][nt][r] * sc3);
            qh[(row * Hh + h) * Dd + (nt << 4) + l15] = *(unsigned short*)&hv;
          }
        } else {
          const int hkv = (nc0 - 512) >> 6;
#pragma unroll
          for (int nt = 0; nt < 4; ++nt) {
            __fp16 hv = (__fp16)(acc[mt][nt][r] * sc2);
            kh[(row * HKV + hkv) * Dd + (nt << 4) + l15] = *(unsigned short*)&hv;
          }
        }
      }
    }
  } else {
    // v transposed: vT[((b*HKV+hkv)*64 + d)*512 + t], 4 consecutive t per store
    const int hkv = (nc0 - 768) >> 6;
#pragma unroll
    for (int mt = 0; mt < 4; ++mt) {
      const int rowbase = m0 + wr + (mt << 4) + rowq;
      const int bb = rowbase >> 9;
      const int trow = rowbase & 511;
#pragma unroll
      for (int nt = 0; nt < 4; ++nt) {
        const int d = (nt << 4) + l15;
        unsigned u0 = h2u(__builtin_amdgcn_cvt_pkrtz(acc[mt][nt][0], acc[mt][nt][1]));
        unsigned u1 = h2u(__builtin_amdgcn_cvt_pkrtz(acc[mt][nt][2], acc[mt][nt][3]));
        *(uint2*)&vT[((bb * HKV + hkv) * 64 + d) * 512 + trow] = make_uint2(u0, u1);
      }
    }
  }
}

// ---------------- Proj MFMA GEMM: 64x64 tile, padded LDS ----------------
__global__ __launch_bounds__(256) void proj_mfma(
    const unsigned short* __restrict__ yb, const unsigned short* __restrict__ Wt,
    float* __restrict__ out) {
  __shared__ unsigned short As[64][72];
  __shared__ unsigned short Bs[64][72];
  const int m0 = blockIdx.x * 64;
  const int n0 = blockIdx.y * 64;
  const int t = threadIdx.x;
  const int w = t >> 6, lane = t & 63;
  const int srow = t >> 2, sc = (t & 3) << 4;
  float4v acc[4] = {{0,0,0,0},{0,0,0,0},{0,0,0,0},{0,0,0,0}};
  for (int k0 = 0; k0 < 512; k0 += 64) {
    uint4 a0 = *(const uint4*)&yb[(m0 + srow) * 512 + k0 + sc];
    uint4 a1 = *(const uint4*)&yb[(m0 + srow) * 512 + k0 + sc + 8];
    uint4 b0 = *(const uint4*)&Wt[(n0 + srow) * 512 + k0 + sc];
    uint4 b1 = *(const uint4*)&Wt[(n0 + srow) * 512 + k0 + sc + 8];
    __syncthreads();
    *(uint4*)&As[srow][sc] = a0; *(uint4*)&As[srow][sc + 8] = a1;
    *(uint4*)&Bs[srow][sc] = b0; *(uint4*)&Bs[srow][sc + 8] = b1;
    __syncthreads();
    const int ml = (w << 4) + (lane & 15);
    const int kq = (lane >> 4) << 3;
    short8 aF0 = *(short8*)&As[ml][kq];
    short8 aF1 = *(short8*)&As[ml][kq + 32];
#pragma unroll
    for (int nt = 0; nt < 4; ++nt) {
      const int nl = (nt << 4) + (lane & 15);
      short8 bF0 = *(short8*)&Bs[nl][kq];
      short8 bF1 = *(short8*)&Bs[nl][kq + 32];
      acc[nt] = __builtin_amdgcn_mfma_f32_16x16x32_bf16(aF0, bF0, acc[nt], 0, 0, 0);
      acc[nt] = __builtin_amdgcn_mfma_f32_16x16x32_bf16(aF1, bF1, acc[nt], 0, 0, 0);
    }
  }
#pragma unroll
  for (int nt = 0; nt < 4; ++nt) {
    int col = n0 + (nt << 4) + (lane & 15);
#pragma unroll
    for (int r = 0; r < 4; ++r) {
      int row = m0 + (w << 4) + ((lane >> 4) << 2) + r;
      out[row * 512 + col] = acc[nt][r];
    }
  }
}

// ---------------- Attention v16 = v9 exact (proven 49.4us) ----------------
// 5 attn experiments (occupancy x3, barriers, ILP) all neutral-or-worse; VALU-busy
// ~26us invariant across all variants. Reverting to the empirically best structure.
// Only delta vs v9: sm_scale is pre-folded into qh (sv = sr, no *0.125).
__global__ __launch_bounds__(256) void attn(
    const unsigned short* __restrict__ qh, const unsigned short* __restrict__ kh,
    const unsigned short* __restrict__ vT, const unsigned short* __restrict__ Pwh,
    unsigned short* __restrict__ yb) {
  __shared__ __fp16 PwS[96][72];
  __shared__ __fp16 pS[32][72];   // padded: A-frag start bank = 4*(i+joct) -> 2-way
  __shared__ float lS[32];

  const int t = threadIdx.x;
  const int lane = t & 63;
  const int wu = __builtin_amdgcn_readfirstlane(t >> 6);
  const int bh = blockIdx.x;
  const int b = bh >> 3;
  const int h = bh & 7;
  const int hkv = h >> 1;
  const int i0 = 480 - blockIdx.y * 32;  // heavy blocks first (order IS the schedule)

  float l_lane[8];
#pragma unroll
  for (int r = 0; r < 8; ++r) l_lane[r] = 0.0f;
  float4v oacc[2] = {{0, 0, 0, 0}, {0, 0, 0, 0}};

  const int prow = (wu << 3) + 63 - lane;
  const int i_base = i0 + (wu << 3);
  const unsigned short* qbase = &qh[((b * Tt + i_base) * Hh + h) * Dd];

  // PV fragment roles
  const int i16 = (wu & 1) << 4;        // A-operand i-tile base row in pS
  const int dt0 = (wu >> 1) << 1;       // first of 2 d-tiles
  const int lm = lane & 15;
  const int kq = (lane >> 4) << 3;      // k (j) octet within 32-half
  const unsigned short* vTbase = &vT[((b * HKV + hkv) * 64) * 512];

  for (int jt0 = 0; jt0 <= i0 + 31; jt0 += 64) {
    __syncthreads();   // guards PwS restage + pS rewrite vs prior PV reads
    {
      int jr = t >> 2, dc = (t & 3) << 4;
      const int pb0 = h * 1023 + (i0 - jt0) + 448;
      const unsigned short* pwp = &Pwh[(pb0 + jr) * 64 + dc];
      *(uint4*)&PwS[jr][dc]     = *(const uint4*)&pwp[0];
      *(uint4*)&PwS[jr][dc + 8] = *(const uint4*)&pwp[8];
      int pr2 = 64 + (t >> 3), dc2 = (t & 7) << 3;
      if (pr2 < 95)
        *(uint4*)&PwS[pr2][dc2] = *(const uint4*)&Pwh[(pb0 + pr2) * 64 + dc2];
    }
    uint4 kr[8];
    {
      const uint4* kp = (const uint4*)&kh[((b * Tt + jt0 + lane) * HKV + hkv) * Dd];
#pragma unroll
      for (int c = 0; c < 8; ++c) kr[c] = kp[c];
    }
    __syncthreads();   // PwS ready

    // ---- score phase: lane = j; q broadcast from global, Pw from LDS, K regs ----
    const int j = jt0 + lane;
#pragma unroll
    for (int r = 0; r < 8; ++r) {
      const uint4* qp = (const uint4*)&qbase[r * (Hh * Dd)];  // wave-uniform
      float sr = 0.0f;
#pragma unroll
      for (int ch = 0; ch < 8; ++ch) {
        uint4 qu = qp[ch];
        uint4 pu = *(uint4*)&PwS[prow + r][ch << 3];
        sr = fdot2(u2h(qu.x) * u2h(pu.x), u2h(kr[ch].x), sr);
        sr = fdot2(u2h(qu.y) * u2h(pu.y), u2h(kr[ch].y), sr);
        sr = fdot2(u2h(qu.z) * u2h(pu.z), u2h(kr[ch].z), sr);
        sr = fdot2(u2h(qu.w) * u2h(pu.w), u2h(kr[ch].w), sr);
      }
      float sv = (j <= i_base + r) ? sr : -1e30f;   // sm_scale pre-folded in qh
      float p = __expf(sv - 6.0f);   // fixed shift: exact softmax, no reduce
      l_lane[r] += p;
      pS[(wu << 3) + r][lane] = (__fp16)p;   // b16 store, 2-way banks
    }
    __syncthreads();   // pS ready for all waves

    // ---- PV phase: MFMA f16, A from pS, B from vT (global, L1/L2-hot) ----
    half8 a0 = *(half8*)&pS[i16 + lm][kq];
    half8 a1 = *(half8*)&pS[i16 + lm][kq + 32];
#pragma unroll
    for (int dd = 0; dd < 2; ++dd) {
      const unsigned short* vp = vTbase + (((dt0 + dd) << 4) + lm) * 512 + jt0 + kq;
      half8 b0 = *(const half8*)&vp[0];
      half8 b1 = *(const half8*)&vp[32];
      oacc[dd] = __builtin_amdgcn_mfma_f32_16x16x32_f16(a0, b0, oacc[dd], 0, 0, 0);
      oacc[dd] = __builtin_amdgcn_mfma_f32_16x16x32_f16(a1, b1, oacc[dd], 0, 0, 0);
    }
  }

  // final l reduction (once), shared via lS (score rows != C-layout rows)
#pragma unroll
  for (int r = 0; r < 8; ++r) {
    float lr = wave_reduce_sum(l_lane[r]);
    if (lane == r) lS[(wu << 3) + r] = lr;
  }
  __syncthreads();

  // epilogue: C layout — row = i16 + quad*4 + reg, col = d-tile*16 + lm
#pragma unroll
  for (int dd = 0; dd < 2; ++dd) {
    const int d = ((dt0 + dd) << 4) + lm;
#pragma unroll
    for (int r = 0; r < 4; ++r) {
      const int irow = i16 + ((lane >> 4) << 2) + r;
      const float val = oacc[dd][r] / lS[irow];
      __hip_bfloat16 hv = __float2bfloat16(val);
      yb[((b * Tt + i0 + irow) * Hh + h) * Dd + d] = *(unsigned short*)&hv;
    }
  }
}

extern "C" void kernel_launch(void* const* d_in, const int* in_sizes, int n_in,
                              void* d_out, int out_size, void* d_ws, size_t ws_size,
                              hipStream_t stream) {
  const float* x     = (const float*)d_in[0];
  const float* Wq    = (const float*)d_in[1];
  const float* Wk    = (const float*)d_in[2];
  const float* Wv    = (const float*)d_in[3];
  const float* Wproj = (const float*)d_in[4];
  const float* P     = (const float*)d_in[5];
  const float* sigma = (const float*)d_in[6];
  float* out = (float*)d_out;

  float* ws = (float*)d_ws;
  unsigned short* qh  = (unsigned short*)ws;                // 2,097,152 h = 1,048,576 f
  unsigned short* kh  = (unsigned short*)(ws + 1048576);    // 1,048,576 h = 524,288 f
  unsigned short* vT  = (unsigned short*)(ws + 1572864);    // 1,048,576 h = 524,288 f (transposed)
  unsigned short* Pwh = (unsigned short*)(ws + 2097152);    // 523,776 h -> 262,144 f
  unsigned short* xb  = (unsigned short*)(ws + 2359296);    // 2M bf16 = 1,048,576 f
  unsigned short* yb  = xb;                                 // alias: xb dead after qkv_mfma
  unsigned short* Wtq = (unsigned short*)(ws + 3407872);    // 524,288 h = 262,144 f
  unsigned short* Wtp = (unsigned short*)(ws + 3670016);    // 262,144 h = 131,072 f

  prep<<<dim3(3262), 256, 0, stream>>>(x, Wq, Wk, Wv, Wproj, P, sigma,
                                       xb, Wtq, Wtp, Pwh);
  qkv_mfma<<<dim3(32, 8), 256, 0, stream>>>(xb, Wtq, qh, kh, vT);
  attn<<<dim3(64, 16), 256, 0, stream>>>(qh, kh, vT, Pwh, yb);
  proj_mfma<<<dim3(64, 8), 256, 0, stream>>>(yb, Wtp, out);
}

// Round 10
// 148.181 us; speedup vs baseline: 1.0353x; 1.0353x over previous
//
#include <hip/hip_runtime.h>
#include <hip/hip_bf16.h>
#include <math.h>

#define Bb 8
#define Tt 512
#define Cc 512
#define Hh 8
#define HKV 4
#define Dd 64

typedef __attribute__((ext_vector_type(8))) short short8;
typedef __attribute__((ext_vector_type(4))) float float4v;
typedef __attribute__((ext_vector_type(2))) __fp16 h2;   // matches cvt_pkrtz return
typedef __attribute__((ext_vector_type(8))) __fp16 half8; // f16 MFMA fragment

__device__ __forceinline__ h2 u2h(unsigned u) {
  union { unsigned u; h2 h; } x; x.u = u; return x.h;
}
__device__ __forceinline__ unsigned h2u(h2 h) {
  union { h2 h; unsigned u; } x; x.h = h; return x.u;
}
__device__ __forceinline__ float fdot2(h2 a, h2 b, float c) {
#if __has_builtin(__builtin_amdgcn_fdot2)
  return __builtin_amdgcn_fdot2(a, b, c, false);
#else
  return fmaf((float)a.x, (float)b.x, fmaf((float)a.y, (float)b.y, c));
#endif
}

__device__ __forceinline__ float wave_reduce_sum(float v) {
#pragma unroll
  for (int off = 32; off > 0; off >>= 1) v += __shfl_xor(v, off, 64);
  return v;
}
__device__ __forceinline__ unsigned pack_bf2(float a, float b) {
  __hip_bfloat162 h = __float22bfloat162_rn(make_float2(a, b));
  return *(unsigned*)&h;
}

// ---------------- fused prep: conv_x | conv_w | build_pw (by block range) ----------------
__global__ __launch_bounds__(256) void prep(
    const float* __restrict__ x, const float* __restrict__ Wq,
    const float* __restrict__ Wk, const float* __restrict__ Wv,
    const float* __restrict__ Wp, const float* __restrict__ P,
    const float* __restrict__ sigma,
    unsigned short* __restrict__ xb, unsigned short* __restrict__ Wtq,
    unsigned short* __restrict__ Wtp, unsigned short* __restrict__ Pwh) {
  const int bid = blockIdx.x;
  const int t = threadIdx.x;
  if (bid < 1024) {
    int i = (bid * 256 + t) * 8;
    float4 f0 = *(const float4*)&x[i];
    float4 f1 = *(const float4*)&x[i + 4];
    unsigned u[4] = {pack_bf2(f0.x, f0.y), pack_bf2(f0.z, f0.w),
                     pack_bf2(f1.x, f1.y), pack_bf2(f1.z, f1.w)};
    *(uint4*)&xb[i] = *(uint4*)u;
  } else if (bid < 1216) {
    __shared__ float Ts[64][65];
    const int bx = bid - 1024;
    const int k0 = (bx & 7) << 6;
    const int n0 = (bx >> 3) << 6;
    const float* src; int ld, nc0; unsigned short* dst; int ndst;
    if (n0 < 512)       { src = Wq; ld = 512; nc0 = n0;        dst = Wtq; ndst = n0; }
    else if (n0 < 768)  { src = Wk; ld = 256; nc0 = n0 - 512;  dst = Wtq; ndst = n0; }
    else if (n0 < 1024) { src = Wv; ld = 256; nc0 = n0 - 768;  dst = Wtq; ndst = n0; }
    else                { src = Wp; ld = 512; nc0 = n0 - 1024; dst = Wtp; ndst = n0 - 1024; }
    const int r = t >> 4, c4 = (t & 15) << 2;
#pragma unroll
    for (int rr = 0; rr < 4; ++rr) {
      int row = (rr << 4) + r;
      float4 f = *(const float4*)&src[(k0 + row) * ld + nc0 + c4];
      Ts[row][c4] = f.x; Ts[row][c4 + 1] = f.y;
      Ts[row][c4 + 2] = f.z; Ts[row][c4 + 3] = f.w;
    }
    __syncthreads();
#pragma unroll
    for (int rr = 0; rr < 4; ++rr) {
      int nr = (rr << 4) + r;
      unsigned u0 = pack_bf2(Ts[c4][nr], Ts[c4 + 1][nr]);
      unsigned u1 = pack_bf2(Ts[c4 + 2][nr], Ts[c4 + 3][nr]);
      *(uint2*)&dst[(ndst + nr) * 512 + k0 + c4] = make_uint2(u0, u1);
    }
  } else {
    int idx = (bid - 1216) * 256 + t;
    int d = idx & 63;
    int rem = idx >> 6;
    int dd = rem % 1023;
    int h = rem / 1023;
    float s = fabsf(sigma[h]) + 1e-6f;
    float delta = (float)(dd - 511);
    float dt = 128.0f * tanhf(delta / s) + 128.0f;
    float lo = floorf(dt);
    int ilo = (int)lo;
    float frac = dt - lo;
    ilo = max(0, min(ilo, 256));
    int ihi = min(ilo + 1, 256);
    const float* Pb = P + h * 257 * 64;
    float val = (1.0f - frac) * Pb[ilo * 64 + d] + frac * Pb[ihi * 64 + d];
    __fp16 hv = (__fp16)val;
    Pwh[idx] = *(unsigned short*)&hv;
  }
}

// ---------------- QKV MFMA GEMM: 64x64 tile (proven best: 1024 blocks = 4/CU) ----------------
// v16 lesson: 128^2 tile -> 256 blocks = 1/CU = no latency hiding, +16us. Keep 64^2.
// sm_scale (1/8) folded into the q store.
__global__ __launch_bounds__(256) void qkv_mfma(
    const unsigned short* __restrict__ xb, const unsigned short* __restrict__ Wt,
    unsigned short* __restrict__ qh, unsigned short* __restrict__ kh,
    unsigned short* __restrict__ vT) {
  __shared__ unsigned short As[64][72];
  __shared__ unsigned short Bs[64][72];
  const int m0 = blockIdx.x * 64;
  const int n0 = blockIdx.y * 64;
  const int t = threadIdx.x;
  const int w = t >> 6, lane = t & 63;
  const int srow = t >> 2, sc = (t & 3) << 4;
  float4v acc[4] = {{0,0,0,0},{0,0,0,0},{0,0,0,0},{0,0,0,0}};
  for (int k0 = 0; k0 < 512; k0 += 64) {
    uint4 a0 = *(const uint4*)&xb[(m0 + srow) * 512 + k0 + sc];
    uint4 a1 = *(const uint4*)&xb[(m0 + srow) * 512 + k0 + sc + 8];
    uint4 b0 = *(const uint4*)&Wt[(n0 + srow) * 512 + k0 + sc];
    uint4 b1 = *(const uint4*)&Wt[(n0 + srow) * 512 + k0 + sc + 8];
    __syncthreads();
    *(uint4*)&As[srow][sc] = a0; *(uint4*)&As[srow][sc + 8] = a1;
    *(uint4*)&Bs[srow][sc] = b0; *(uint4*)&Bs[srow][sc + 8] = b1;
    __syncthreads();
    const int ml = (w << 4) + (lane & 15);
    const int kq = (lane >> 4) << 3;
    short8 aF0 = *(short8*)&As[ml][kq];
    short8 aF1 = *(short8*)&As[ml][kq + 32];
#pragma unroll
    for (int nt = 0; nt < 4; ++nt) {
      const int nl = (nt << 4) + (lane & 15);
      short8 bF0 = *(short8*)&Bs[nl][kq];
      short8 bF1 = *(short8*)&Bs[nl][kq + 32];
      acc[nt] = __builtin_amdgcn_mfma_f32_16x16x32_bf16(aF0, bF0, acc[nt], 0, 0, 0);
      acc[nt] = __builtin_amdgcn_mfma_f32_16x16x32_bf16(aF1, bF1, acc[nt], 0, 0, 0);
    }
  }
  const int lane15 = lane & 15;
  const int rowbase = m0 + (w << 4) + ((lane >> 4) << 2);
  if (n0 < 768) {
    // q or k head: fused RMS-norm over the 64-wide head (= this n-tile)
#pragma unroll
    for (int r = 0; r < 4; ++r) {
      float ss = 0.0f;
#pragma unroll
      for (int nt = 0; nt < 4; ++nt) ss = fmaf(acc[nt][r], acc[nt][r], ss);
#pragma unroll
      for (int off = 1; off < 16; off <<= 1) ss += __shfl_xor(ss, off, 64);
      float sc2 = 8.0f * rsqrtf(ss + 1e-6f);
      const int row = rowbase + r;
      if (n0 < 512) {
        const int h = n0 >> 6;
        const float sc3 = sc2 * 0.125f;   // fold sm_scale into q
#pragma unroll
        for (int nt = 0; nt < 4; ++nt) {
          __fp16 hv = (__fp16)(acc[nt][r] * sc3);
          qh[(row * Hh + h) * Dd + (nt << 4) + lane15] = *(unsigned short*)&hv;
        }
      } else {
        const int hkv = (n0 - 512) >> 6;
#pragma unroll
        for (int nt = 0; nt < 4; ++nt) {
          __fp16 hv = (__fp16)(acc[nt][r] * sc2);
          kh[(row * HKV + hkv) * Dd + (nt << 4) + lane15] = *(unsigned short*)&hv;
        }
      }
    }
  } else {
    // v transposed: vT[((b*HKV+hkv)*64 + d)*512 + t], 4 consecutive t per store
    const int hkv = (n0 - 768) >> 6;
    const int bb = rowbase >> 9;       // batch (64-row tile is within one b)
    const int trow = rowbase & 511;
#pragma unroll
    for (int nt = 0; nt < 4; ++nt) {
      const int d = (nt << 4) + lane15;
      unsigned u0 = h2u(__builtin_amdgcn_cvt_pkrtz(acc[nt][0], acc[nt][1]));
      unsigned u1 = h2u(__builtin_amdgcn_cvt_pkrtz(acc[nt][2], acc[nt][3]));
      *(uint2*)&vT[((bb * HKV + hkv) * 64 + d) * 512 + trow] = make_uint2(u0, u1);
    }
  }
}

// ---------------- Proj MFMA GEMM: 64x64 tile, padded LDS ----------------
__global__ __launch_bounds__(256) void proj_mfma(
    const unsigned short* __restrict__ yb, const unsigned short* __restrict__ Wt,
    float* __restrict__ out) {
  __shared__ unsigned short As[64][72];
  __shared__ unsigned short Bs[64][72];
  const int m0 = blockIdx.x * 64;
  const int n0 = blockIdx.y * 64;
  const int t = threadIdx.x;
  const int w = t >> 6, lane = t & 63;
  const int srow = t >> 2, sc = (t & 3) << 4;
  float4v acc[4] = {{0,0,0,0},{0,0,0,0},{0,0,0,0},{0,0,0,0}};
  for (int k0 = 0; k0 < 512; k0 += 64) {
    uint4 a0 = *(const uint4*)&yb[(m0 + srow) * 512 + k0 + sc];
    uint4 a1 = *(const uint4*)&yb[(m0 + srow) * 512 + k0 + sc + 8];
    uint4 b0 = *(const uint4*)&Wt[(n0 + srow) * 512 + k0 + sc];
    uint4 b1 = *(const uint4*)&Wt[(n0 + srow) * 512 + k0 + sc + 8];
    __syncthreads();
    *(uint4*)&As[srow][sc] = a0; *(uint4*)&As[srow][sc + 8] = a1;
    *(uint4*)&Bs[srow][sc] = b0; *(uint4*)&Bs[srow][sc + 8] = b1;
    __syncthreads();
    const int ml = (w << 4) + (lane & 15);
    const int kq = (lane >> 4) << 3;
    short8 aF0 = *(short8*)&As[ml][kq];
    short8 aF1 = *(short8*)&As[ml][kq + 32];
#pragma unroll
    for (int nt = 0; nt < 4; ++nt) {
      const int nl = (nt << 4) + (lane & 15);
      short8 bF0 = *(short8*)&Bs[nl][kq];
      short8 bF1 = *(short8*)&Bs[nl][kq + 32];
      acc[nt] = __builtin_amdgcn_mfma_f32_16x16x32_bf16(aF0, bF0, acc[nt], 0, 0, 0);
      acc[nt] = __builtin_amdgcn_mfma_f32_16x16x32_bf16(aF1, bF1, acc[nt], 0, 0, 0);
    }
  }
#pragma unroll
  for (int nt = 0; nt < 4; ++nt) {
    int col = n0 + (nt << 4) + (lane & 15);
#pragma unroll
    for (int r = 0; r < 4; ++r) {
      int row = m0 + (w << 4) + ((lane >> 4) << 2) + r;
      out[row * 512 + col] = acc[nt][r];
    }
  }
}

// ---------------- Attention v17: 128-wide j-tiles (halve per-iter overhead) ----------------
// Invariants across v9..v16: core VALU issue ~7.7us, VALU-busy ~26us, wall ~49.4us ->
// 3.4x instruction bloat is per-ITERATION overhead (staging, q reloads, barriers, addr).
// v11 proved overhead ~ iteration count. v17 keeps v9 geometry but processes 128 j's
// per iteration (each lane owns j=jt0+lane and jt0+64+lane): barriers -50%, q loads
// -50%, PwS staging -16%, same core ops (+11% masked waste on small tiles).
// Iterations 4608 -> 2560. LDS ~31.9KB (still 4 blk/CU). VGPR must stay <=128.
__global__ __launch_bounds__(256) void attn(
    const unsigned short* __restrict__ qh, const unsigned short* __restrict__ kh,
    const unsigned short* __restrict__ vT, const unsigned short* __restrict__ Pwh,
    unsigned short* __restrict__ yb) {
  __shared__ __fp16 PwS[160][72];   // 159 rows used: deltas (i0-jt0-127)..(i0-jt0+31)
  __shared__ __fp16 pS[32][136];    // 128 cols + pad (row stride 272B = 4-bank shift)
  __shared__ float lS[32];

  const int t = threadIdx.x;
  const int lane = t & 63;
  const int wu = __builtin_amdgcn_readfirstlane(t >> 6);
  const int bh = blockIdx.x;
  const int b = bh >> 3;
  const int h = bh & 7;
  const int hkv = h >> 1;
  const int i0 = 480 - blockIdx.y * 32;  // heavy blocks first (order IS the schedule)

  float l_lane[8];
#pragma unroll
  for (int r = 0; r < 8; ++r) l_lane[r] = 0.0f;
  float4v oacc[2] = {{0, 0, 0, 0}, {0, 0, 0, 0}};

  const int prowA = (wu << 3) + 127 - lane;   // PwS row for j = jt0+lane   (r=0)
  const int prowB = (wu << 3) + 63 - lane;    // PwS row for j = jt0+64+lane (r=0)
  const int i_base = i0 + (wu << 3);
  const unsigned short* qbase = &qh[((b * Tt + i_base) * Hh + h) * Dd];

  // PV fragment roles
  const int i16 = (wu & 1) << 4;        // A-operand i-tile base row in pS
  const int dt0 = (wu >> 1) << 1;       // first of 2 d-tiles
  const int lm = lane & 15;
  const int kq = (lane >> 4) << 3;      // k (j) octet within 64-half
  const unsigned short* vTbase = &vT[((b * HKV + hkv) * 64) * 512];

  for (int jt0 = 0; jt0 < i0 + 32; jt0 += 128) {
    __syncthreads();   // guards PwS restage + pS rewrite vs prior PV reads
    {
      // stage 159 rows x 64 fp16 = 1272 uint4 slots, 5 rounds of 256 threads
      const int pb0 = h * 1023 + (i0 - jt0) + 384;   // row 0 = delta (i0-jt0-127)+511
      int s = t;
#pragma unroll
      for (int rnd = 0; rnd < 5; ++rnd) {
        if (s < 1272) {
          int r = s >> 3, c = (s & 7) << 3;
          *(uint4*)&PwS[r][c] = *(const uint4*)&Pwh[(pb0 + r) * 64 + c];
        }
        s += 256;
      }
    }
    uint4 kra[8], krb[8];
    {
      const uint4* kpa = (const uint4*)&kh[((b * Tt + jt0 + lane) * HKV + hkv) * Dd];
      const uint4* kpb = (const uint4*)&kh[((b * Tt + jt0 + 64 + lane) * HKV + hkv) * Dd];
#pragma unroll
      for (int c = 0; c < 8; ++c) { kra[c] = kpa[c]; krb[c] = kpb[c]; }
    }
    __syncthreads();   // PwS ready

    // ---- score phase: lane owns two j's; q broadcast, Pw from LDS, K regs ----
    const int ja = jt0 + lane;
    const int jb = jt0 + 64 + lane;
#pragma unroll
    for (int r = 0; r < 8; ++r) {
      const uint4* qp = (const uint4*)&qbase[r * (Hh * Dd)];  // wave-uniform
      float sa = 0.0f, sb = 0.0f;
#pragma unroll
      for (int ch = 0; ch < 8; ++ch) {
        uint4 qu = qp[ch];
        uint4 pa = *(uint4*)&PwS[prowA + r][ch << 3];
        uint4 pb = *(uint4*)&PwS[prowB + r][ch << 3];
        h2 qx = u2h(qu.x), qy = u2h(qu.y), qz = u2h(qu.z), qw = u2h(qu.w);
        sa = fdot2(qx * u2h(pa.x), u2h(kra[ch].x), sa);
        sa = fdot2(qy * u2h(pa.y), u2h(kra[ch].y), sa);
        sa = fdot2(qz * u2h(pa.z), u2h(kra[ch].z), sa);
        sa = fdot2(qw * u2h(pa.w), u2h(kra[ch].w), sa);
        sb = fdot2(qx * u2h(pb.x), u2h(krb[ch].x), sb);
        sb = fdot2(qy * u2h(pb.y), u2h(krb[ch].y), sb);
        sb = fdot2(qz * u2h(pb.z), u2h(krb[ch].z), sb);
        sb = fdot2(qw * u2h(pb.w), u2h(krb[ch].w), sb);
      }
      float sva = (ja <= i_base + r) ? sa : -1e30f;   // sm_scale pre-folded in qh
      float svb = (jb <= i_base + r) ? sb : -1e30f;
      float pva = __expf(sva - 6.0f);   // fixed shift: exact softmax, no reduce
      float pvb = __expf(svb - 6.0f);
      l_lane[r] += pva + pvb;
      pS[(wu << 3) + r][lane] = (__fp16)pva;
      pS[(wu << 3) + r][lane + 64] = (__fp16)pvb;
    }
    __syncthreads();   // pS ready for all waves

    // ---- PV phase: MFMA f16 K=128, A from pS, B from vT (global, L1/L2-hot) ----
    half8 a0 = *(half8*)&pS[i16 + lm][kq];
    half8 a1 = *(half8*)&pS[i16 + lm][kq + 32];
    half8 a2 = *(half8*)&pS[i16 + lm][kq + 64];
    half8 a3 = *(half8*)&pS[i16 + lm][kq + 96];
#pragma unroll
    for (int dd = 0; dd < 2; ++dd) {
      const unsigned short* vp = vTbase + (((dt0 + dd) << 4) + lm) * 512 + jt0 + kq;
      half8 b0 = *(const half8*)&vp[0];
      half8 b1 = *(const half8*)&vp[32];
      half8 b2 = *(const half8*)&vp[64];
      half8 b3 = *(const half8*)&vp[96];
      oacc[dd] = __builtin_amdgcn_mfma_f32_16x16x32_f16(a0, b0, oacc[dd], 0, 0, 0);
      oacc[dd] = __builtin_amdgcn_mfma_f32_16x16x32_f16(a1, b1, oacc[dd], 0, 0, 0);
      oacc[dd] = __builtin_amdgcn_mfma_f32_16x16x32_f16(a2, b2, oacc[dd], 0, 0, 0);
      oacc[dd] = __builtin_amdgcn_mfma_f32_16x16x32_f16(a3, b3, oacc[dd], 0, 0, 0);
    }
  }

  // final l reduction (once), shared via lS (score rows != C-layout rows)
#pragma unroll
  for (int r = 0; r < 8; ++r) {
    float lr = wave_reduce_sum(l_lane[r]);
    if (lane == r) lS[(wu << 3) + r] = lr;
  }
  __syncthreads();

  // epilogue: C layout — row = i16 + quad*4 + reg, col = d-tile*16 + lm
#pragma unroll
  for (int dd = 0; dd < 2; ++dd) {
    const int d = ((dt0 + dd) << 4) + lm;
#pragma unroll
    for (int r = 0; r < 4; ++r) {
      const int irow = i16 + ((lane >> 4) << 2) + r;
      const float val = oacc[dd][r] / lS[irow];
      __hip_bfloat16 hv = __float2bfloat16(val);
      yb[((b * Tt + i0 + irow) * Hh + h) * Dd + d] = *(unsigned short*)&hv;
    }
  }
}

extern "C" void kernel_launch(void* const* d_in, const int* in_sizes, int n_in,
                              void* d_out, int out_size, void* d_ws, size_t ws_size,
                              hipStream_t stream) {
  const float* x     = (const float*)d_in[0];
  const float* Wq    = (const float*)d_in[1];
  const float* Wk    = (const float*)d_in[2];
  const float* Wv    = (const float*)d_in[3];
  const float* Wproj = (const float*)d_in[4];
  const float* P     = (const float*)d_in[5];
  const float* sigma = (const float*)d_in[6];
  float* out = (float*)d_out;

  float* ws = (float*)d_ws;
  unsigned short* qh  = (unsigned short*)ws;                // 2,097,152 h = 1,048,576 f
  unsigned short* kh  = (unsigned short*)(ws + 1048576);    // 1,048,576 h = 524,288 f
  unsigned short* vT  = (unsigned short*)(ws + 1572864);    // 1,048,576 h = 524,288 f (transposed)
  unsigned short* Pwh = (unsigned short*)(ws + 2097152);    // 523,776 h -> 262,144 f
  unsigned short* xb  = (unsigned short*)(ws + 2359296);    // 2M bf16 = 1,048,576 f
  unsigned short* yb  = xb;                                 // alias: xb dead after qkv_mfma
  unsigned short* Wtq = (unsigned short*)(ws + 3407872);    // 524,288 h = 262,144 f
  unsigned short* Wtp = (unsigned short*)(ws + 3670016);    // 262,144 h = 131,072 f

  prep<<<dim3(3262), 256, 0, stream>>>(x, Wq, Wk, Wv, Wproj, P, sigma,
                                       xb, Wtq, Wtp, Pwh);
  qkv_mfma<<<dim3(64, 16), 256, 0, stream>>>(xb, Wtq, qh, kh, vT);
  attn<<<dim3(64, 16), 256, 0, stream>>>(qh, kh, vT, Pwh, yb);
  proj_mfma<<<dim3(64, 8), 256, 0, stream>>>(yb, Wtp, out);
}